// Round 10
// baseline (272.659 us; speedup 1.0000x reference)
//
#include <hip/hip_runtime.h>
#include <hip/hip_bf16.h>
#include <stdint.h>

#define N_ROWS 512
#define D_DIM  512
#define C_CLS  100000
#define C_PAD  100096           // 391*256

#define SCALE_F    64.0f
#define EPS_F      1e-7f
#define COS_M_F    0.8775825618903728f
#define SIN_M_F    0.4794255386042030f
#define THRESH_F  -0.8775825618903728f
#define MM_F       0.2397127693021015f
#define FIXMAX_F   65.0f        // fixed softmax max: all logits <= 64*1.01 < 65

#define NG 391          // col-groups of 256

// ---- ws layout (bytes) ----
#define XN_OFF     0                          // bf16 bits [512][512]
#define XNORM_OFF  (XN_OFF + 512*512*2)       // f32 [512]
#define TL_OFF     (XNORM_OFF + 2048)         // f32 [512]
#define CTM_OFF    (TL_OFF + 2048)            // f32 [512]
#define FTL_OFF    (CTM_OFF + 2048)           // f32 [512]
#define TNEW_OFF   (FTL_OFF + 2048)           // f32 [1] (padded)
#define PSUM_OFF   (TNEW_OFF + 256)           // f32 [512][NG]
#define LOSSI_OFF  (PSUM_OFF + 512*NG*4)      // f32 [512]

typedef __attribute__((ext_vector_type(8))) short bf16x8;
typedef __attribute__((ext_vector_type(4))) float f32x4;

#define GLOAD_LDS16(gp, lp) \
    __builtin_amdgcn_global_load_lds((const __attribute__((address_space(1))) void*)(gp), \
                                     (__attribute__((address_space(3))) void*)(lp), 16, 0, 0)

__device__ inline unsigned short f2bf(float f) {
    union { float f; unsigned int u; } a; a.f = f;
    unsigned int r = (a.u + 0x7FFFu + ((a.u >> 16) & 1u)) >> 16;
    return (unsigned short)r;
}

__device__ inline float wave_sum64(float v) {
    #pragma unroll
    for (int m = 1; m < 64; m <<= 1) v += __shfl_xor(v, m);
    return v;
}

// K1: x row norms + xn bf16.  grid 512 x 64
__global__ void k_xnorm(const float* __restrict__ x,
                        unsigned short* __restrict__ xn,
                        float* __restrict__ xnorm) {
    int row = blockIdx.x;
    int lane = threadIdx.x;
    const float* xr = x + row * D_DIM + lane * 8;
    float4 v0 = *(const float4*)(xr);
    float4 v1 = *(const float4*)(xr + 4);
    float s = v0.x*v0.x + v0.y*v0.y + v0.z*v0.z + v0.w*v0.w
            + v1.x*v1.x + v1.y*v1.y + v1.z*v1.z + v1.w*v1.w;
    s = wave_sum64(s);
    float nrm = sqrtf(s);
    if (lane == 0) xnorm[row] = nrm;
    float inv = 1.0f / nrm;
    union { unsigned short h[8]; uint4 q; } u;
    u.h[0]=f2bf(v0.x*inv); u.h[1]=f2bf(v0.y*inv); u.h[2]=f2bf(v0.z*inv); u.h[3]=f2bf(v0.w*inv);
    u.h[4]=f2bf(v1.x*inv); u.h[5]=f2bf(v1.y*inv); u.h[6]=f2bf(v1.z*inv); u.h[7]=f2bf(v1.w*inv);
    *(uint4*)(xn + row * D_DIM + lane * 8) = u.q;
}

// K2: per-row target logit + margin terms; target w-norm computed INLINE.
// grid 512 x 64
__global__ void k_tlogit(const float* __restrict__ x, const float* __restrict__ w,
                         const float* __restrict__ xnorm,
                         const int* __restrict__ target,
                         float* __restrict__ tl, float* __restrict__ ctm,
                         float* __restrict__ ftl) {
    int row = blockIdx.x;
    int lane = threadIdx.x;
    int tgt = target[row];
    const float* xr = x + row * D_DIM + lane * 8;
    const float* wr = w + (size_t)tgt * D_DIM + lane * 8;
    float4 a0 = *(const float4*)(xr),     a1 = *(const float4*)(xr + 4);
    float4 b0 = *(const float4*)(wr),     b1 = *(const float4*)(wr + 4);
    float s = a0.x*b0.x + a0.y*b0.y + a0.z*b0.z + a0.w*b0.w
            + a1.x*b1.x + a1.y*b1.y + a1.z*b1.z + a1.w*b1.w;
    float q = b0.x*b0.x + b0.y*b0.y + b0.z*b0.z + b0.w*b0.w
            + b1.x*b1.x + b1.y*b1.y + b1.z*b1.z + b1.w*b1.w;
    s = wave_sum64(s);
    q = wave_sum64(q);
    if (lane == 0) {
        float c = s / (xnorm[row] * sqrtf(q));
        c = fminf(fmaxf(c, -1.0f + EPS_F), 1.0f - EPS_F);
        float sn = sqrtf(fmaxf(1.0f - c * c, 0.0f));
        float cm = c * COS_M_F - sn * SIN_M_F;
        tl[row]  = c;
        ctm[row] = cm;
        ftl[row] = (c > THRESH_F) ? cm : (c - MM_F);
    }
}

// K2b: t_new = mean(tl)*0.01 + 0.99*t.  1 x 512
__global__ void k_tnew(const float* __restrict__ tl, const float* __restrict__ t,
                       float* __restrict__ tnew) {
    __shared__ float s[512];
    int tid = threadIdx.x;
    s[tid] = tl[tid];
    __syncthreads();
    for (int off = 256; off > 0; off >>= 1) {
        if (tid < off) s[tid] += s[tid + off];
        __syncthreads();
    }
    if (tid == 0) tnew[0] = (s[0] / 512.0f) * 0.01f + 0.99f * t[0];
}

// ---------------------------------------------------------------------------
// K3: single-pass streaming GEMM over RAW f32 weights.
//  - No wnorm pre-pass, no bf16-W materialization: B lanes load f32, convert
//    to bf16 in-register, and accumulate sum-of-squares inline; the per-class
//    1/||w|| is applied as a column scale in the epilogue (2 shuffles/class).
//  - block = 8 waves (512 thr), 64 A-rows, 256 classes; wave owns 32 classes.
//  - A staged ONCE (64KB, frag-major [kk][m][1KB], conflict-free ds_read);
//    ONE pre-compute barrier.  B ring depth 4.
//  - fixed softmax max (=65): exp+sum only, no max reduce.
//  - w is read HERE only (205 MB first-touch; 7/8 mb-siblings hit XCD L2).
// grid 3128 x 512
// ---------------------------------------------------------------------------
__global__ __launch_bounds__(512) void k_gemm_f32b(
        const unsigned short* __restrict__ xn,    // bf16 [512][512]
        const float* __restrict__ w,              // f32 [100000][512] RAW
        const int* __restrict__ target,
        const float* __restrict__ ctm,
        const float* __restrict__ ftl,
        const float* __restrict__ tnew,
        float* __restrict__ psum) {
    __shared__ unsigned short As[16 * 4 * 512];   // 64 KB, [kk][m][1KB frag]
    __shared__ int   tgt_s[64];
    __shared__ float ctm_s[64];
    __shared__ float ftl_s[64];
    __shared__ float redS[8][64];

    // XCD remap: 3128 = 8*391; all 8 mb-siblings of an ng share one XCD.
    int bx = blockIdx.x;
    int logical = (bx & 7) * 391 + (bx >> 3);
    int ng = logical >> 3, mb = logical & 7;
    int rowbase = mb * 64;

    int tid = threadIdx.x;
    int lane = tid & 63, wid = tid >> 6;       // wid 0..7
    int fr = lane & 15, rgrp = lane >> 4;
    int cb = ng * 256 + wid * 32;              // this wave's first class (32)

    if (tid < 64) {
        int rg = rowbase + tid;
        tgt_s[tid] = target[rg];
        ctm_s[tid] = ctm[rg];
        ftl_s[tid] = ftl[rg];
    }

    const char* Ab = (const char*)xn;     // row stride 1024 B

    // ---- B lane base pointers (j-tile j): class = cb + j*16 + fr ----
    // Clamp OOB classes (>= C_CLS, last ng only) to row 0; their logits are
    // forced to -3e38 in the epilogue.
    const float* bptr[2];
    bool cvalid[2];
    #pragma unroll
    for (int j = 0; j < 2; j++) {
        int cgl = cb + j * 16 + fr;
        cvalid[j] = (cgl < C_CLS);
        int crow = cvalid[j] ? cgl : 0;
        bptr[j] = w + (size_t)crow * D_DIM + rgrp * 8;
    }

    float sumsq[2] = {0.0f, 0.0f};

    // load f32 slice (8 floats), accumulate sumsq, convert to bf16x8
    #define LOADCVT(j, kkv, dst)                                             \
        do {                                                                 \
            const float* p_ = bptr[j] + (kkv) * 32;                          \
            float4 u0_ = *(const float4*)(p_);                               \
            float4 u1_ = *(const float4*)(p_ + 4);                           \
            sumsq[j] += u0_.x*u0_.x + u0_.y*u0_.y + u0_.z*u0_.z + u0_.w*u0_.w\
                      + u1_.x*u1_.x + u1_.y*u1_.y + u1_.z*u1_.z + u1_.w*u1_.w;\
            union { unsigned short h[8]; bf16x8 v; } t_;                     \
            t_.h[0]=f2bf(u0_.x); t_.h[1]=f2bf(u0_.y);                        \
            t_.h[2]=f2bf(u0_.z); t_.h[3]=f2bf(u0_.w);                        \
            t_.h[4]=f2bf(u1_.x); t_.h[5]=f2bf(u1_.y);                        \
            t_.h[6]=f2bf(u1_.z); t_.h[7]=f2bf(u1_.w);                        \
            dst = t_.v;                                                      \
        } while (0)

    // ---- B preloads kk=0..3 (depth-4 ring) ----
    bf16x8 bv[4][2];
    #pragma unroll
    for (int d = 0; d < 4; d++) {
        LOADCVT(0, d, bv[d][0]);
        LOADCVT(1, d, bv[d][1]);
    }

    // ---- stage full A (64 chunks of 1 KB, 8 per wave): c = kk*4+m ----
    int asrow = lane >> 2, askb = (lane & 3) * 16;
    #pragma unroll
    for (int cc = 0; cc < 8; ++cc) {
        int c = wid * 8 + cc;
        int kk = c >> 2, m = c & 3;
        GLOAD_LDS16(Ab + (size_t)(rowbase + m * 16 + asrow) * 1024 + kk * 64 + askb,
                    (char*)As + c * 1024);
    }
    __syncthreads();                           // the ONLY pre-compute barrier

    float tn = tnew[0];
    int albase = fr * 64 + rgrp * 16;          // reader offset within a frag

    f32x4 acc[4][2];                           // [m][j]
    #pragma unroll
    for (int m = 0; m < 4; m++)
        #pragma unroll
        for (int j = 0; j < 2; j++)
            acc[m][j] = (f32x4){0.f, 0.f, 0.f, 0.f};

    bf16x8 af[2][4];
    #pragma unroll
    for (int m = 0; m < 4; m++)
        af[0][m] = *(const bf16x8*)((const char*)As + m * 1024 + albase);

    #pragma unroll
    for (int kk = 0; kk < 16; ++kk) {
        int cur = kk & 1;
        if (kk < 15) {
            #pragma unroll
            for (int m = 0; m < 4; m++)
                af[cur ^ 1][m] = *(const bf16x8*)((const char*)As
                                 + ((kk + 1) * 4 + m) * 1024 + albase);
        }
        if (kk < 12) {   // reload ring slot for kk+4, before the MFMA cluster
            LOADCVT(0, kk + 4, bv[kk & 3][0]);
            LOADCVT(1, kk + 4, bv[kk & 3][1]);
        }
        __builtin_amdgcn_s_setprio(1);
        #pragma unroll
        for (int m = 0; m < 4; m++)
            #pragma unroll
            for (int j = 0; j < 2; j++)
                acc[m][j] = __builtin_amdgcn_mfma_f32_16x16x32_bf16(
                                af[cur][m], bv[kk & 3][j], acc[m][j], 0, 0, 0);
        __builtin_amdgcn_s_setprio(0);
    }
    #undef LOADCVT

    // ---- column scale 1/||w||: combine the 4 rgrp-slices of sumsq ----
    float inv[2];
    #pragma unroll
    for (int j = 0; j < 2; j++) {
        float s2 = sumsq[j];
        s2 += __shfl_xor(s2, 16);
        s2 += __shfl_xor(s2, 32);
        inv[j] = rsqrtf(s2);
    }

    // ---- epilogue: fixed-max (65) transform + exp + row sum ----
    // C/D layout: col = cb + j*16 + fr, row = m*16 + rgrp*4 + reg.
    #pragma unroll
    for (int m = 0; m < 4; m++) {
        #pragma unroll
        for (int reg = 0; reg < 4; reg++) {
            int rl = m * 16 + rgrp * 4 + reg;
            int tr = tgt_s[rl];
            float cm = ctm_s[rl];
            float ft = ftl_s[rl];
            float sm = 0.0f;
            #pragma unroll
            for (int j = 0; j < 2; j++) {
                int col = cb + j * 16 + fr;
                float c = acc[m][j][reg] * inv[j];
                c = fminf(fmaxf(c, -1.0f + EPS_F), 1.0f - EPS_F);
                float v = (c > cm) ? c * (tn + c) : c;
                v *= SCALE_F;
                v = (col == tr) ? ft * SCALE_F : v;
                v = cvalid[j] ? v : -3.0e38f;   // exp -> 0 (also kills NaN)
                sm += __expf(v - FIXMAX_F);
            }
            #pragma unroll
            for (int msk = 1; msk < 16; msk <<= 1) sm += __shfl_xor(sm, msk);
            if (fr == 0) redS[wid][rl] = sm;
        }
    }
    __syncthreads();
    if (tid < 64) {
        float S = 0.0f;
        #pragma unroll
        for (int wv = 0; wv < 8; wv++) S += redS[wv][tid];
        psum[(size_t)(rowbase + tid) * NG + ng] = S;
    }
}

// K4: per-row sum over NG partials (fixed max) -> loss_i.  grid 512 x 256
__global__ void k_rowlse_fix(const float* __restrict__ psum,
                             const float* __restrict__ ftl,
                             float* __restrict__ lossi) {
    int row = blockIdx.x, tid = threadIdx.x;
    float S = 0.0f;
    for (int nb = tid; nb < NG; nb += 256) S += psum[(size_t)row * NG + nb];
    __shared__ float sS[256];
    sS[tid] = S;
    __syncthreads();
    for (int off = 128; off > 0; off >>= 1) {
        if (tid < off) sS[tid] += sS[tid + off];
        __syncthreads();
    }
    if (tid == 0) lossi[row] = logf(sS[0]) + FIXMAX_F - SCALE_F * ftl[row];
}

// K5: loss = mean(loss_i).  1 x 512
__global__ void k_final(const float* __restrict__ lossi, float* __restrict__ out) {
    __shared__ float s[512];
    int tid = threadIdx.x;
    s[tid] = lossi[tid];
    __syncthreads();
    for (int off = 256; off > 0; off >>= 1) {
        if (tid < off) s[tid] += s[tid + off];
        __syncthreads();
    }
    if (tid == 0) out[0] = s[0] / 512.0f;
}

extern "C" void kernel_launch(void* const* d_in, const int* in_sizes, int n_in,
                              void* d_out, int out_size, void* d_ws, size_t ws_size,
                              hipStream_t stream) {
    const float* x      = (const float*)d_in[0];
    const float* w      = (const float*)d_in[1];
    const float* t      = (const float*)d_in[2];
    const int*   target = (const int*)d_in[3];

    char* ws = (char*)d_ws;
    unsigned short* xn  = (unsigned short*)(ws + XN_OFF);
    float* xnorm = (float*)(ws + XNORM_OFF);
    float* tl    = (float*)(ws + TL_OFF);
    float* ctm   = (float*)(ws + CTM_OFF);
    float* ftl   = (float*)(ws + FTL_OFF);
    float* tnew  = (float*)(ws + TNEW_OFF);
    float* psum  = (float*)(ws + PSUM_OFF);
    float* lossi = (float*)(ws + LOSSI_OFF);
    float* out   = (float*)d_out;

    k_xnorm<<<dim3(N_ROWS), dim3(64), 0, stream>>>(x, xn, xnorm);
    k_tlogit<<<dim3(N_ROWS), dim3(64), 0, stream>>>(x, w, xnorm, target, tl, ctm, ftl);
    k_tnew<<<dim3(1), dim3(512), 0, stream>>>(tl, t, tnew);
    k_gemm_f32b<<<dim3(8 * NG), dim3(512), 0, stream>>>(xn, w, target, ctm, ftl, tnew, psum);
    k_rowlse_fix<<<dim3(N_ROWS), dim3(256), 0, stream>>>(psum, ftl, lossi);
    k_final<<<dim3(1), dim3(512), 0, stream>>>(lossi, out);
}

// Round 11
// 149.069 us; speedup vs baseline: 1.8291x; 1.8291x over previous
//
#include <hip/hip_runtime.h>
#include <hip/hip_bf16.h>
#include <stdint.h>

#define N_ROWS 512
#define D_DIM  512
#define C_CLS  100000

#define SCALE_F    64.0f
#define EPS_F      1e-7f
#define COS_M_F    0.8775825618903728f
#define SIN_M_F    0.4794255386042030f
#define THRESH_F  -0.8775825618903728f
#define MM_F       0.2397127693021015f
#define FIXMAX_F   65.0f        // fixed softmax max: all logits <= ~64.7 < 65

#define NG 391          // col-groups of 256

// ---- ws layout (bytes) ----
#define XN8_OFF    0                          // fp8 [512][512] = 256 KB
#define TL_OFF     (XN8_OFF + 512*512)        // f32 [512]
#define CTM_OFF    (TL_OFF + 2048)            // f32 [512]
#define FTL_OFF    (CTM_OFF + 2048)           // f32 [512]
#define TNEW_OFF   (FTL_OFF + 2048)           // f32 [1] (padded)
#define XNORM_OFF  (TNEW_OFF + 256)           // f32 [512]
#define PSUM_OFF   (XNORM_OFF + 2048)         // f32 [512][NG]
#define LOSSI_OFF  (PSUM_OFF + 512*NG*4)      // f32 [512]
#define WNB8_OFF   (LOSSI_OFF + 2048)         // fp8 [100096][512] = 51.25 MB

typedef __attribute__((ext_vector_type(4))) float f32x4;

#define GLOAD_LDS16(gp, lp) \
    __builtin_amdgcn_global_load_lds((const __attribute__((address_space(1))) void*)(gp), \
                                     (__attribute__((address_space(3))) void*)(lp), 16, 0, 0)

#if defined(__has_builtin)
#if __has_builtin(__builtin_amdgcn_cvt_pk_fp8_f32)
#define HAVE_CVT_FP8 1
#endif
#endif

// manual OCP e4m3fn fallback (round-to-nearest; saturating; no inf)
__device__ inline unsigned char f2e4m3(float f) {
    union { float f; unsigned u; } a; a.f = f;
    unsigned s = (a.u >> 24) & 0x80u;
    float af = fabsf(f);
    if (af < 0.015625f) {                       // subnormal: q/512, q<=8
        int q = (int)(af * 512.0f + 0.5f);
        return (unsigned char)(s | (unsigned)q);
    }
    unsigned x = a.u & 0x7FFFFFFFu;
    unsigned r = x + 0x000FFFFFu + ((x >> 20) & 1u);   // rne to 3 mant bits
    int ec = (int)(r >> 23) - 127 + 7;
    unsigned m = (r >> 20) & 7u;
    if (ec > 15 || (ec == 15 && m == 7u)) return (unsigned char)(s | 0x7Eu); // 448
    return (unsigned char)(s | ((unsigned)ec << 3) | m);
}

// pack 8 f32 -> 8 fp8 bytes
__device__ inline uint2 pack8_fp8(float f0, float f1, float f2, float f3,
                                  float f4, float f5, float f6, float f7) {
#ifdef HAVE_CVT_FP8
    int w0 = __builtin_amdgcn_cvt_pk_fp8_f32(f0, f1, 0, false);
    w0     = __builtin_amdgcn_cvt_pk_fp8_f32(f2, f3, w0, true);
    int w1 = __builtin_amdgcn_cvt_pk_fp8_f32(f4, f5, 0, false);
    w1     = __builtin_amdgcn_cvt_pk_fp8_f32(f6, f7, w1, true);
    uint2 r; r.x = (unsigned)w0; r.y = (unsigned)w1;
    return r;
#else
    union { unsigned char b[8]; uint2 q; } u;
    u.b[0]=f2e4m3(f0); u.b[1]=f2e4m3(f1); u.b[2]=f2e4m3(f2); u.b[3]=f2e4m3(f3);
    u.b[4]=f2e4m3(f4); u.b[5]=f2e4m3(f5); u.b[6]=f2e4m3(f6); u.b[7]=f2e4m3(f7);
    return u.q;
#endif
}

__device__ inline float wave_sum64(float v) {
    #pragma unroll
    for (int m = 1; m < 64; m <<= 1) v += __shfl_xor(v, m);
    return v;
}

// K1: x row norms + xn fp8.  grid 512 x 64
__global__ void k_xnorm_fp8(const float* __restrict__ x,
                            unsigned char* __restrict__ xn8,
                            float* __restrict__ xnorm) {
    int row = blockIdx.x;
    int lane = threadIdx.x;
    const float* xr = x + row * D_DIM + lane * 8;
    float4 v0 = *(const float4*)(xr);
    float4 v1 = *(const float4*)(xr + 4);
    float s = v0.x*v0.x + v0.y*v0.y + v0.z*v0.z + v0.w*v0.w
            + v1.x*v1.x + v1.y*v1.y + v1.z*v1.z + v1.w*v1.w;
    s = wave_sum64(s);
    float nrm = sqrtf(s);
    if (lane == 0) xnorm[row] = nrm;
    float inv = 1.0f / nrm;
    uint2 q = pack8_fp8(v0.x*inv, v0.y*inv, v0.z*inv, v0.w*inv,
                        v1.x*inv, v1.y*inv, v1.z*inv, v1.w*inv);
    *(uint2*)(xn8 + row * D_DIM + lane * 8) = q;
}

// K2: weight row norms + normalized fp8 W (pad rows zeroed).
// NT loads keep wnb8 L3-resident for the GEMM.  grid 25024 x 256
__global__ void k_wnorm_fp8(const float* __restrict__ w,
                            unsigned char* __restrict__ wnb8) {
    int row = blockIdx.x * 4 + (threadIdx.x >> 6);
    int lane = threadIdx.x & 63;
    if (row < C_CLS) {
        const float* wr = w + (size_t)row * D_DIM + lane * 8;
        f32x4 v0 = __builtin_nontemporal_load((const f32x4*)(wr));
        f32x4 v1 = __builtin_nontemporal_load((const f32x4*)(wr + 4));
        float s = v0.x*v0.x + v0.y*v0.y + v0.z*v0.z + v0.w*v0.w
                + v1.x*v1.x + v1.y*v1.y + v1.z*v1.z + v1.w*v1.w;
        s = wave_sum64(s);
        float inv = rsqrtf(s);
        uint2 q = pack8_fp8(v0.x*inv, v0.y*inv, v0.z*inv, v0.w*inv,
                            v1.x*inv, v1.y*inv, v1.z*inv, v1.w*inv);
        *(uint2*)(wnb8 + (size_t)row * D_DIM + lane * 8) = q;
    } else {
        uint2 z = {0u, 0u};
        *(uint2*)(wnb8 + (size_t)row * D_DIM + lane * 8) = z;
    }
}

// K3: per-row target logit + margin terms; target w-norm computed inline.
// grid 512 x 64
__global__ void k_tlogit(const float* __restrict__ x, const float* __restrict__ w,
                         const float* __restrict__ xnorm,
                         const int* __restrict__ target,
                         float* __restrict__ tl, float* __restrict__ ctm,
                         float* __restrict__ ftl) {
    int row = blockIdx.x;
    int lane = threadIdx.x;
    int tgt = target[row];
    const float* xr = x + row * D_DIM + lane * 8;
    const float* wr = w + (size_t)tgt * D_DIM + lane * 8;
    float4 a0 = *(const float4*)(xr),     a1 = *(const float4*)(xr + 4);
    float4 b0 = *(const float4*)(wr),     b1 = *(const float4*)(wr + 4);
    float s = a0.x*b0.x + a0.y*b0.y + a0.z*b0.z + a0.w*b0.w
            + a1.x*b1.x + a1.y*b1.y + a1.z*b1.z + a1.w*b1.w;
    float q = b0.x*b0.x + b0.y*b0.y + b0.z*b0.z + b0.w*b0.w
            + b1.x*b1.x + b1.y*b1.y + b1.z*b1.z + b1.w*b1.w;
    s = wave_sum64(s);
    q = wave_sum64(q);
    if (lane == 0) {
        float c = s / (xnorm[row] * sqrtf(q));
        c = fminf(fmaxf(c, -1.0f + EPS_F), 1.0f - EPS_F);
        float sn = sqrtf(fmaxf(1.0f - c * c, 0.0f));
        float cm = c * COS_M_F - sn * SIN_M_F;
        tl[row]  = c;
        ctm[row] = cm;
        ftl[row] = (c > THRESH_F) ? cm : (c - MM_F);
    }
}

// K3b: t_new = mean(tl)*0.01 + 0.99*t.  1 x 512
__global__ void k_tnew(const float* __restrict__ tl, const float* __restrict__ t,
                       float* __restrict__ tnew) {
    __shared__ float s[512];
    int tid = threadIdx.x;
    s[tid] = tl[tid];
    __syncthreads();
    for (int off = 256; off > 0; off >>= 1) {
        if (tid < off) s[tid] += s[tid + off];
        __syncthreads();
    }
    if (tid == 0) tnew[0] = (s[0] / 512.0f) * 0.01f + 0.99f * t[0];
}

// ---------------------------------------------------------------------------
// K4: fp8 streaming GEMM (r9 structure, half the bytes).
//  - block = 8 waves (512 thr), 64 A-rows, 256 classes; wave owns 32 classes.
//  - A: 32 KB LDS, row-major [64][512B] with XOR-16 swizzle (pre-swizzled
//    global_load_lds source; same XOR on ds_read_b64 side — rule #21).
//    Staged once; ONE pre-compute barrier.
//  - B: fp8 rows stream global->VGPR (8 B/lane/kk), depth-6 ring.
//  - mfma_f32_16x16x32_fp8_fp8; fixed softmax max (=65): exp+sum only.
// grid 3128 x 512
// ---------------------------------------------------------------------------
__global__ __launch_bounds__(512) void k_gemm_fp8(
        const unsigned char* __restrict__ xn8,    // fp8 [512][512]
        const unsigned char* __restrict__ wnb8,   // fp8 [100096][512], normalized
        const int* __restrict__ target,
        const float* __restrict__ ctm,
        const float* __restrict__ ftl,
        const float* __restrict__ tnew,
        float* __restrict__ psum) {
    __shared__ unsigned char As[64 * 512];        // 32 KB
    __shared__ int   tgt_s[64];
    __shared__ float ctm_s[64];
    __shared__ float ftl_s[64];
    __shared__ float redS[8][64];

    // XCD remap: 3128 = 8*391; all 8 mb-siblings of an ng share one XCD.
    int bx = blockIdx.x;
    int logical = (bx & 7) * 391 + (bx >> 3);
    int ng = logical >> 3, mb = logical & 7;
    int rowbase = mb * 64;

    int tid = threadIdx.x;
    int lane = tid & 63, wid = tid >> 6;       // wid 0..7
    int fr = lane & 15, rgrp = lane >> 4;
    int cb = ng * 256 + wid * 32;              // this wave's first class (32)

    if (tid < 64) {
        int rg = rowbase + tid;
        tgt_s[tid] = target[rg];
        ctm_s[tid] = ctm[rg];
        ftl_s[tid] = ftl[rg];
    }

    // ---- B lane base pointers (j-tile j): class = cb + j*16 + fr ----
    const unsigned char* bptr[2];
    bool cvalid[2];
    #pragma unroll
    for (int j = 0; j < 2; j++) {
        int cgl = cb + j * 16 + fr;
        cvalid[j] = (cgl < C_CLS);
        bptr[j] = wnb8 + (size_t)cgl * D_DIM + rgrp * 8;   // pad rows are zeroed
    }

    // ---- B preloads kk=0..5 (depth-6 ring) ----
    uint2 bv[6][2];
    #pragma unroll
    for (int d = 0; d < 6; d++)
        #pragma unroll
        for (int j = 0; j < 2; j++)
            bv[d][j] = *(const uint2*)(bptr[j] + d * 32);

    // ---- stage A (32 KB): wave wid stages bytes [wid*4096, +4096) in 4 calls
    // of 1 KB.  LDS (row, b) holds source byte (rowbase+row, b ^ ((row&7)<<4)).
    #pragma unroll
    for (int c2 = 0; c2 < 4; ++c2) {
        int lo = wid * 4096 + c2 * 1024;       // wave-uniform LDS base
        int o  = lo + lane * 16;
        int row = o >> 9;
        int b   = (o & 511) ^ ((row & 7) << 4);
        GLOAD_LDS16(xn8 + (size_t)(rowbase + row) * 512 + b, (char*)As + lo);
    }
    __syncthreads();                           // the ONLY pre-compute barrier

    float tn = tnew[0];
    int key = (fr & 7) << 4;                   // read-side XOR (row&7 == fr&7)

    f32x4 acc[4][2];                           // [m][j]
    #pragma unroll
    for (int m = 0; m < 4; m++)
        #pragma unroll
        for (int j = 0; j < 2; j++)
            acc[m][j] = (f32x4){0.f, 0.f, 0.f, 0.f};

    union LL { uint2 u; long long ll; };

    uint2 af[2][4];
    #pragma unroll
    for (int m = 0; m < 4; m++)
        af[0][m] = *(const uint2*)(As + (m * 16 + fr) * 512 + ((rgrp * 8) ^ key));

    #pragma unroll
    for (int kk = 0; kk < 16; ++kk) {
        int cur = kk & 1;
        if (kk < 15) {
            #pragma unroll
            for (int m = 0; m < 4; m++)
                af[cur ^ 1][m] = *(const uint2*)(As + (m * 16 + fr) * 512
                                 + (((kk + 1) * 32 + rgrp * 8) ^ key));
        }
        if (kk < 10) {   // reload ring slot for kk+6, before the MFMA cluster
            #pragma unroll
            for (int j = 0; j < 2; j++)
                bv[(kk + 6) % 6][j] = *(const uint2*)(bptr[j] + (kk + 6) * 32);
        }
        __builtin_amdgcn_s_setprio(1);
        #pragma unroll
        for (int m = 0; m < 4; m++)
            #pragma unroll
            for (int j = 0; j < 2; j++) {
                LL a, b;
                a.u = af[cur][m];
                b.u = bv[kk % 6][j];
                acc[m][j] = __builtin_amdgcn_mfma_f32_16x16x32_fp8_fp8(
                                a.ll, b.ll, acc[m][j], 0, 0, 0);
            }
        __builtin_amdgcn_s_setprio(0);
    }

    // ---- epilogue: fixed-max (65) transform + exp + row sum ----
    // C/D layout: col = cb + j*16 + fr, row = m*16 + rgrp*4 + reg.
    #pragma unroll
    for (int m = 0; m < 4; m++) {
        #pragma unroll
        for (int reg = 0; reg < 4; reg++) {
            int rl = m * 16 + rgrp * 4 + reg;
            int tr = tgt_s[rl];
            float cm = ctm_s[rl];
            float ft = ftl_s[rl];
            float sm = 0.0f;
            #pragma unroll
            for (int j = 0; j < 2; j++) {
                int col = cb + j * 16 + fr;
                float c = acc[m][j][reg];
                c = fminf(fmaxf(c, -1.0f + EPS_F), 1.0f - EPS_F);
                float v = (c > cm) ? c * (tn + c) : c;
                v *= SCALE_F;
                v = (col == tr) ? ft * SCALE_F : v;
                v = cvalid[j] ? v : -3.0e38f;   // exp -> 0
                sm += __expf(v - FIXMAX_F);
            }
            #pragma unroll
            for (int msk = 1; msk < 16; msk <<= 1) sm += __shfl_xor(sm, msk);
            if (fr == 0) redS[wid][rl] = sm;
        }
    }
    __syncthreads();
    if (tid < 64) {
        float S = 0.0f;
        #pragma unroll
        for (int wv = 0; wv < 8; wv++) S += redS[wv][tid];
        psum[(size_t)(rowbase + tid) * NG + ng] = S;
    }
}

// K5: per-row sum over NG partials (fixed max) -> loss_i.  grid 512 x 256
__global__ void k_rowlse_fix(const float* __restrict__ psum,
                             const float* __restrict__ ftl,
                             float* __restrict__ lossi) {
    int row = blockIdx.x, tid = threadIdx.x;
    float S = 0.0f;
    for (int nb = tid; nb < NG; nb += 256) S += psum[(size_t)row * NG + nb];
    __shared__ float sS[256];
    sS[tid] = S;
    __syncthreads();
    for (int off = 128; off > 0; off >>= 1) {
        if (tid < off) sS[tid] += sS[tid + off];
        __syncthreads();
    }
    if (tid == 0) lossi[row] = logf(sS[0]) + FIXMAX_F - SCALE_F * ftl[row];
}

// K6: loss = mean(loss_i).  1 x 512
__global__ void k_final(const float* __restrict__ lossi, float* __restrict__ out) {
    __shared__ float s[512];
    int tid = threadIdx.x;
    s[tid] = lossi[tid];
    __syncthreads();
    for (int off = 256; off > 0; off >>= 1) {
        if (tid < off) s[tid] += s[tid + off];
        __syncthreads();
    }
    if (tid == 0) out[0] = s[0] / 512.0f;
}

extern "C" void kernel_launch(void* const* d_in, const int* in_sizes, int n_in,
                              void* d_out, int out_size, void* d_ws, size_t ws_size,
                              hipStream_t stream) {
    const float* x      = (const float*)d_in[0];
    const float* w      = (const float*)d_in[1];
    const float* t      = (const float*)d_in[2];
    const int*   target = (const int*)d_in[3];

    char* ws = (char*)d_ws;
    unsigned char* xn8  = (unsigned char*)(ws + XN8_OFF);
    float* tl    = (float*)(ws + TL_OFF);
    float* ctm   = (float*)(ws + CTM_OFF);
    float* ftl   = (float*)(ws + FTL_OFF);
    float* tnew  = (float*)(ws + TNEW_OFF);
    float* xnorm = (float*)(ws + XNORM_OFF);
    float* psum  = (float*)(ws + PSUM_OFF);
    float* lossi = (float*)(ws + LOSSI_OFF);
    unsigned char* wnb8 = (unsigned char*)(ws + WNB8_OFF);
    float* out   = (float*)d_out;

    k_xnorm_fp8<<<dim3(N_ROWS), dim3(64), 0, stream>>>(x, xn8, xnorm);
    k_tlogit<<<dim3(N_ROWS), dim3(64), 0, stream>>>(x, w, xnorm, target, tl, ctm, ftl);
    k_tnew<<<dim3(1), dim3(512), 0, stream>>>(tl, t, tnew);
    k_wnorm_fp8<<<dim3((C_CLS + 3) / 4 + 6, 1), dim3(256), 0, stream>>>(w, wnb8);
    k_gemm_fp8<<<dim3(8 * NG), dim3(512), 0, stream>>>(xn8, wnb8, target, ctm, ftl, tnew, psum);
    k_rowlse_fix<<<dim3(N_ROWS), dim3(256), 0, stream>>>(psum, ftl, lossi);
    k_final<<<dim3(1), dim3(512), 0, stream>>>(lossi, out);
}

// Round 12
// 121.870 us; speedup vs baseline: 2.2373x; 1.2232x over previous
//
#include <hip/hip_runtime.h>
#include <hip/hip_bf16.h>
#include <stdint.h>

#define N_ROWS 512
#define D_DIM  512
#define C_CLS  100000

#define SCALE_F    64.0f
#define EPS_F      1e-7f
#define COS_M_F    0.8775825618903728f
#define SIN_M_F    0.4794255386042030f
#define THRESH_F  -0.8775825618903728f
#define MM_F       0.2397127693021015f
#define FIXMAX_F   65.0f        // fixed softmax max: all logits <= ~64.7 < 65

#define NC  64          // classes per block
#define NG2 1564        // ceil(100000/64) -> 1564*64 = 100096

// ---- ws layout (bytes) ----
#define XN8_OFF    0                          // fp8 [512][512] = 256 KB
#define TL_OFF     (XN8_OFF + 512*512)        // f32 [512]
#define CTM_OFF    (TL_OFF + 2048)            // f32 [512]
#define FTL_OFF    (CTM_OFF + 2048)           // f32 [512]
#define TNEW_OFF   (FTL_OFF + 2048)           // f32 [1] (padded)
#define XNORM_OFF  (TNEW_OFF + 256)           // f32 [512]
#define PSUM_OFF   (XNORM_OFF + 2048)         // f32 [512][NG2] = 3.2 MB
#define LOSSI_OFF  (PSUM_OFF + 512*NG2*4)     // f32 [512]

typedef __attribute__((ext_vector_type(4))) float f32x4;

#define GLOAD_LDS16(gp, lp) \
    __builtin_amdgcn_global_load_lds((const __attribute__((address_space(1))) void*)(gp), \
                                     (__attribute__((address_space(3))) void*)(lp), 16, 0, 0)

#if defined(__has_builtin)
#if __has_builtin(__builtin_amdgcn_cvt_pk_fp8_f32)
#define HAVE_CVT_FP8 1
#endif
#endif

// manual OCP e4m3fn fallback (round-to-nearest; saturating; no inf)
__device__ inline unsigned char f2e4m3(float f) {
    union { float f; unsigned u; } a; a.f = f;
    unsigned s = (a.u >> 24) & 0x80u;
    float af = fabsf(f);
    if (af < 0.015625f) {
        int q = (int)(af * 512.0f + 0.5f);
        return (unsigned char)(s | (unsigned)q);
    }
    unsigned x = a.u & 0x7FFFFFFFu;
    unsigned r = x + 0x000FFFFFu + ((x >> 20) & 1u);
    int ec = (int)(r >> 23) - 127 + 7;
    unsigned m = (r >> 20) & 7u;
    if (ec > 15 || (ec == 15 && m == 7u)) return (unsigned char)(s | 0x7Eu);
    return (unsigned char)(s | ((unsigned)ec << 3) | m);
}

__device__ inline unsigned pack4_fp8(float f0, float f1, float f2, float f3) {
#ifdef HAVE_CVT_FP8
    int q = __builtin_amdgcn_cvt_pk_fp8_f32(f0, f1, 0, false);
    q     = __builtin_amdgcn_cvt_pk_fp8_f32(f2, f3, q, true);
    return (unsigned)q;
#else
    union { unsigned char b[4]; unsigned u; } u;
    u.b[0]=f2e4m3(f0); u.b[1]=f2e4m3(f1); u.b[2]=f2e4m3(f2); u.b[3]=f2e4m3(f3);
    return u.u;
#endif
}

__device__ inline uint2 pack8_fp8(float f0, float f1, float f2, float f3,
                                  float f4, float f5, float f6, float f7) {
    uint2 r;
    r.x = pack4_fp8(f0, f1, f2, f3);
    r.y = pack4_fp8(f4, f5, f6, f7);
    return r;
}

__device__ inline float wave_sum64(float v) {
    #pragma unroll
    for (int m = 1; m < 64; m <<= 1) v += __shfl_xor(v, m);
    return v;
}

// K1: x row norms + xn fp8.  grid 512 x 64
__global__ void k_xnorm_fp8(const float* __restrict__ x,
                            unsigned char* __restrict__ xn8,
                            float* __restrict__ xnorm) {
    int row = blockIdx.x;
    int lane = threadIdx.x;
    const float* xr = x + row * D_DIM + lane * 8;
    float4 v0 = *(const float4*)(xr);
    float4 v1 = *(const float4*)(xr + 4);
    float s = v0.x*v0.x + v0.y*v0.y + v0.z*v0.z + v0.w*v0.w
            + v1.x*v1.x + v1.y*v1.y + v1.z*v1.z + v1.w*v1.w;
    s = wave_sum64(s);
    float nrm = sqrtf(s);
    if (lane == 0) xnorm[row] = nrm;
    float inv = 1.0f / nrm;
    uint2 q = pack8_fp8(v0.x*inv, v0.y*inv, v0.z*inv, v0.w*inv,
                        v1.x*inv, v1.y*inv, v1.z*inv, v1.w*inv);
    *(uint2*)(xn8 + row * D_DIM + lane * 8) = q;
}

// K2: per-row target logit + margin terms; target w-norm computed inline.
// grid 512 x 64
__global__ void k_tlogit(const float* __restrict__ x, const float* __restrict__ w,
                         const float* __restrict__ xnorm,
                         const int* __restrict__ target,
                         float* __restrict__ tl, float* __restrict__ ctm,
                         float* __restrict__ ftl) {
    int row = blockIdx.x;
    int lane = threadIdx.x;
    int tgt = target[row];
    const float* xr = x + row * D_DIM + lane * 8;
    const float* wr = w + (size_t)tgt * D_DIM + lane * 8;
    float4 a0 = *(const float4*)(xr),     a1 = *(const float4*)(xr + 4);
    float4 b0 = *(const float4*)(wr),     b1 = *(const float4*)(wr + 4);
    float s = a0.x*b0.x + a0.y*b0.y + a0.z*b0.z + a0.w*b0.w
            + a1.x*b1.x + a1.y*b1.y + a1.z*b1.z + a1.w*b1.w;
    float q = b0.x*b0.x + b0.y*b0.y + b0.z*b0.z + b0.w*b0.w
            + b1.x*b1.x + b1.y*b1.y + b1.z*b1.z + b1.w*b1.w;
    s = wave_sum64(s);
    q = wave_sum64(q);
    if (lane == 0) {
        float c = s / (xnorm[row] * sqrtf(q));
        c = fminf(fmaxf(c, -1.0f + EPS_F), 1.0f - EPS_F);
        float sn = sqrtf(fmaxf(1.0f - c * c, 0.0f));
        float cm = c * COS_M_F - sn * SIN_M_F;
        tl[row]  = c;
        ctm[row] = cm;
        ftl[row] = (c > THRESH_F) ? cm : (c - MM_F);
    }
}

// K2b: t_new = mean(tl)*0.01 + 0.99*t.  1 x 512
__global__ void k_tnew(const float* __restrict__ tl, const float* __restrict__ t,
                       float* __restrict__ tnew) {
    __shared__ float s[512];
    int tid = threadIdx.x;
    s[tid] = tl[tid];
    __syncthreads();
    for (int off = 256; off > 0; off >>= 1) {
        if (tid < off) s[tid] += s[tid + off];
        __syncthreads();
    }
    if (tid == 0) tnew[0] = (s[0] / 512.0f) * 0.01f + 0.99f * t[0];
}

// ---------------------------------------------------------------------------
// K3: FUSED single-pass kernel.  Each block: ALL 512 rows x 64 classes.
//  - w (f32) is read exactly ONCE chip-wide: per step, 64 rows x 128 B
//    coalesced; each thread loads 4 f32, accumulates ||w||^2 inline,
//    converts to fp8 ONCE, ds_writes 4 B into the B double-buffer.
//  - A (xn8, 256 KB, L2-resident) streams per-step via global_load_lds dbuf.
//  - per wave per step: 16 MFMA (fp8 16x16x32); one barrier per step.
//  - 1/||w|| applied as a column scale in the epilogue (invS exchange).
//  - fixed softmax max (=65): exp+sum only; per-row partial -> psum[row][bx].
// grid 1564 x 512
// ---------------------------------------------------------------------------
__global__ __launch_bounds__(512, 4) void k_fused(
        const unsigned char* __restrict__ xn8,    // fp8 [512][512], normalized
        const float* __restrict__ w,              // f32 [100000][512] RAW
        const int* __restrict__ target,
        const float* __restrict__ ctm,
        const float* __restrict__ ftl,
        const float* __restrict__ tnew,
        float* __restrict__ psum) {
    __shared__ unsigned char As[2][512 * 32];     // 2 x 16 KB
    __shared__ unsigned char Bs[2][64 * 32];      // 2 x 2 KB
    __shared__ float invS[64];
    __shared__ int   tgt_s[512];
    __shared__ float ctm_s[512];
    __shared__ float ftl_s[512];

    int bx = blockIdx.x;
    int cb = bx * NC;                  // first class of this block
    int tid = threadIdx.x;
    int lane = tid & 63, wid = tid >> 6;
    int fr = lane & 15, rgrp = lane >> 4;
    int wrow = wid * 64;               // wave's first A-row

    tgt_s[tid] = target[tid];
    ctm_s[tid] = ctm[tid];
    ftl_s[tid] = ftl[tid];

    // ---- B staging assignment: thread -> (class-row, 4-f32 slot) ----
    int brow  = tid >> 3;              // 0..63
    int bslot = tid & 7;               // 0..7
    int bclass = cb + brow;
    bool brvalid = (bclass < C_CLS);
    const float* bsrc = w + (size_t)(brvalid ? bclass : 0) * D_DIM + bslot * 4;

    float sumsq = 0.0f;

    // stage A slice kk into As[buf] (2 x 8 KB global_load_lds, linear)
    #define STAGE_A(kk, buf)                                                  \
        do {                                                                  \
            _Pragma("unroll")                                                 \
            for (int c = 0; c < 2; ++c) {                                     \
                int lo = c * 8192 + wid * 1024;      /* wave-uniform */       \
                int o  = lo + lane * 16;                                      \
                int row = o >> 5, b = o & 31;                                 \
                GLOAD_LDS16(xn8 + (size_t)row * 512 + (kk) * 32 + b,          \
                            (char*)As[buf] + lo);                             \
            }                                                                 \
        } while (0)

    // stage B slice kk into Bs[buf]: load 4 f32, sumsq, cvt fp8, ds_write 4B
    #define STAGE_B(kk, buf)                                                  \
        do {                                                                  \
            float4 v_ = *(const float4*)(bsrc + (kk) * 32);                   \
            sumsq += v_.x*v_.x + v_.y*v_.y + v_.z*v_.z + v_.w*v_.w;           \
            *(unsigned*)(&Bs[buf][brow * 32 + bslot * 4]) =                   \
                pack4_fp8(v_.x, v_.y, v_.z, v_.w);                            \
        } while (0)

    // prologue: stage kk=0
    STAGE_A(0, 0);
    STAGE_B(0, 0);
    __syncthreads();

    float tn = tnew[0];

    f32x4 acc[4][4];                   // [m][j]
    #pragma unroll
    for (int m = 0; m < 4; m++)
        #pragma unroll
        for (int j = 0; j < 4; j++)
            acc[m][j] = (f32x4){0.f, 0.f, 0.f, 0.f};

    union LL { uint2 u; long long ll; };

    for (int kk = 0; kk < 16; ++kk) {
        int cur = kk & 1;
        if (kk < 15) {
            STAGE_A(kk + 1, cur ^ 1);
            STAGE_B(kk + 1, cur ^ 1);
        }
        // frags from current buffers
        uint2 af[4], bf[4];
        #pragma unroll
        for (int m = 0; m < 4; m++)
            af[m] = *(const uint2*)(&As[cur][(wrow + m * 16 + fr) * 32 + rgrp * 8]);
        #pragma unroll
        for (int j = 0; j < 4; j++)
            bf[j] = *(const uint2*)(&Bs[cur][(j * 16 + fr) * 32 + rgrp * 8]);
        __builtin_amdgcn_s_setprio(1);
        #pragma unroll
        for (int m = 0; m < 4; m++)
            #pragma unroll
            for (int j = 0; j < 4; j++) {
                LL a, b;
                a.u = af[m];
                b.u = bf[j];
                acc[m][j] = __builtin_amdgcn_mfma_f32_16x16x32_fp8_fp8(
                                a.ll, b.ll, acc[m][j], 0, 0, 0);
            }
        __builtin_amdgcn_s_setprio(0);
        __syncthreads();               // next-slice staged; buffers handoff
    }
    #undef STAGE_A
    #undef STAGE_B

    // ---- combine sumsq (8 threads per class row) -> invS ----
    float s2 = sumsq;
    s2 += __shfl_xor(s2, 1);
    s2 += __shfl_xor(s2, 2);
    s2 += __shfl_xor(s2, 4);
    if (bslot == 0) invS[brow] = rsqrtf(s2);
    __syncthreads();

    // ---- epilogue: fixed-max transform + exp + row sum ----
    // C/D layout: col = cb + j*16 + fr, row = wrow + m*16 + rgrp*4 + reg.
    float inv[4];
    bool cvalid[4];
    #pragma unroll
    for (int j = 0; j < 4; j++) {
        inv[j] = invS[j * 16 + fr];
        cvalid[j] = (cb + j * 16 + fr) < C_CLS;
    }
    #pragma unroll
    for (int m = 0; m < 4; m++) {
        #pragma unroll
        for (int reg = 0; reg < 4; reg++) {
            int rl = wrow + m * 16 + rgrp * 4 + reg;
            int tr = tgt_s[rl];
            float cm = ctm_s[rl];
            float ft = ftl_s[rl];
            float sm = 0.0f;
            #pragma unroll
            for (int j = 0; j < 4; j++) {
                int col = cb + j * 16 + fr;
                float c = acc[m][j][reg] * inv[j];
                c = fminf(fmaxf(c, -1.0f + EPS_F), 1.0f - EPS_F);
                float v = (c > cm) ? c * (tn + c) : c;
                v *= SCALE_F;
                v = (col == tr) ? ft * SCALE_F : v;
                v = cvalid[j] ? v : -3.0e38f;   // exp -> 0
                sm += __expf(v - FIXMAX_F);
            }
            #pragma unroll
            for (int msk = 1; msk < 16; msk <<= 1) sm += __shfl_xor(sm, msk);
            if (fr == 0) psum[(size_t)rl * NG2 + bx] = sm;
        }
    }
}

// K4: per-row sum over NG2 partials (fixed max) -> loss_i.  grid 512 x 256
__global__ void k_rowlse_fix(const float* __restrict__ psum,
                             const float* __restrict__ ftl,
                             float* __restrict__ lossi) {
    int row = blockIdx.x, tid = threadIdx.x;
    float S = 0.0f;
    for (int nb = tid; nb < NG2; nb += 256) S += psum[(size_t)row * NG2 + nb];
    __shared__ float sS[256];
    sS[tid] = S;
    __syncthreads();
    for (int off = 128; off > 0; off >>= 1) {
        if (tid < off) sS[tid] += sS[tid + off];
        __syncthreads();
    }
    if (tid == 0) lossi[row] = logf(sS[0]) + FIXMAX_F - SCALE_F * ftl[row];
}

// K5: loss = mean(loss_i).  1 x 512
__global__ void k_final(const float* __restrict__ lossi, float* __restrict__ out) {
    __shared__ float s[512];
    int tid = threadIdx.x;
    s[tid] = lossi[tid];
    __syncthreads();
    for (int off = 256; off > 0; off >>= 1) {
        if (tid < off) s[tid] += s[tid + off];
        __syncthreads();
    }
    if (tid == 0) out[0] = s[0] / 512.0f;
}

extern "C" void kernel_launch(void* const* d_in, const int* in_sizes, int n_in,
                              void* d_out, int out_size, void* d_ws, size_t ws_size,
                              hipStream_t stream) {
    const float* x      = (const float*)d_in[0];
    const float* w      = (const float*)d_in[1];
    const float* t      = (const float*)d_in[2];
    const int*   target = (const int*)d_in[3];

    char* ws = (char*)d_ws;
    unsigned char* xn8  = (unsigned char*)(ws + XN8_OFF);
    float* tl    = (float*)(ws + TL_OFF);
    float* ctm   = (float*)(ws + CTM_OFF);
    float* ftl   = (float*)(ws + FTL_OFF);
    float* tnew  = (float*)(ws + TNEW_OFF);
    float* xnorm = (float*)(ws + XNORM_OFF);
    float* psum  = (float*)(ws + PSUM_OFF);
    float* lossi = (float*)(ws + LOSSI_OFF);
    float* out   = (float*)d_out;

    k_xnorm_fp8<<<dim3(N_ROWS), dim3(64), 0, stream>>>(x, xn8, xnorm);
    k_tlogit<<<dim3(N_ROWS), dim3(64), 0, stream>>>(x, w, xnorm, target, tl, ctm, ftl);
    k_tnew<<<dim3(1), dim3(512), 0, stream>>>(tl, t, tnew);
    k_fused<<<dim3(NG2), dim3(512), 0, stream>>>(xn8, w, target, ctm, ftl, tnew, psum);
    k_rowlse_fix<<<dim3(N_ROWS), dim3(256), 0, stream>>>(psum, ftl, lossi);
    k_final<<<dim3(1), dim3(512), 0, stream>>>(lossi, out);
}